// Round 5
// baseline (327.667 us; speedup 1.0000x reference)
//
#include <hip/hip_runtime.h>
#include <hip/hip_bf16.h>

// B=4, Q=K=1024, C=512, H=8, HD=64, OUT=512
// d_out = [output (4*1024*512 f32) | logits_update (4*8*1024*1024 f32)]

typedef float f32x4 __attribute__((ext_vector_type(4)));
typedef __bf16 bf16x8 __attribute__((ext_vector_type(8)));
typedef __bf16 bf16x4 __attribute__((ext_vector_type(4)));

static __device__ __forceinline__ __bf16 f2bf(float x) {
    union { float f; unsigned int u; } c; c.f = x;
    unsigned int r = (c.u + 0x7fffu + ((c.u >> 16) & 1u)) >> 16;
    union { unsigned short s; __bf16 b; } o; o.s = (unsigned short)r;
    return o.b;
}

// async global->LDS, 16B per lane; LDS dest = wave-uniform base + lane*16
static __device__ __forceinline__ void async16(const void* g, void* l) {
    __builtin_amdgcn_global_load_lds(
        (const __attribute__((address_space(1))) void*)g,
        (__attribute__((address_space(3))) void*)l, 16, 0, 0);
}

// ---------------------------------------------------------------------------
// Cast q_data/m_data f32 -> bf16, vectorized (8 elem/thread each).
// ---------------------------------------------------------------------------
__global__ __launch_bounds__(256) void cast_data(
    const float* __restrict__ qd, const float* __restrict__ md,
    __bf16* __restrict__ qdb, __bf16* __restrict__ mdb)
{
    const int i = blockIdx.x * 256 + threadIdx.x;   // 0..262143
    const f32x4* q4 = (const f32x4*)qd;
    const f32x4* m4 = (const f32x4*)md;
    f32x4 a = q4[2 * i], b = q4[2 * i + 1];
    bf16x8 o;
#pragma unroll
    for (int j = 0; j < 4; j++) { o[j] = f2bf(a[j]); o[4 + j] = f2bf(b[j]); }
    *(bf16x8*)&qdb[i * 8] = o;
    a = m4[2 * i]; b = m4[2 * i + 1];
#pragma unroll
    for (int j = 0; j < 4; j++) { o[j] = f2bf(a[j]); o[4 + j] = f2bf(b[j]); }
    *(bf16x8*)&mdb[i * 8] = o;
}

// ---------------------------------------------------------------------------
// Tiled transpose+cast of the five 512x512 weight matrices (z selects).
// out[n*512+a] = in[a*512+n] * scale  (qw gets 1/8 folded in)
// ---------------------------------------------------------------------------
__global__ __launch_bounds__(256) void transpose_cast(
    const float* __restrict__ qw, const float* __restrict__ kw,
    const float* __restrict__ vw, const float* __restrict__ gw,
    const float* __restrict__ ow,
    __bf16* __restrict__ qwt, __bf16* __restrict__ kwt,
    __bf16* __restrict__ vwt, __bf16* __restrict__ gwt,
    __bf16* __restrict__ owt)
{
    __shared__ float tile[64][65];
    const int z = blockIdx.z;
    const float* src = (z == 0) ? qw : (z == 1) ? kw : (z == 2) ? vw : (z == 3) ? gw : ow;
    __bf16* dst = (z == 0) ? qwt : (z == 1) ? kwt : (z == 2) ? vwt : (z == 3) ? gwt : owt;
    const float scale = (z == 0) ? 0.125f : 1.0f;
    const int a0 = blockIdx.x * 64, n0 = blockIdx.y * 64;
    const int t = threadIdx.x, tr = t >> 4, tc = (t & 15) * 4;
#pragma unroll
    for (int ii = 0; ii < 4; ii++) {
        f32x4 v = *(const f32x4*)&src[(a0 + tr + 16 * ii) * 512 + n0 + tc];
#pragma unroll
        for (int j = 0; j < 4; j++) tile[tr + 16 * ii][tc + j] = v[j] * scale;
    }
    __syncthreads();
#pragma unroll
    for (int ii = 0; ii < 4; ii++) {
        const int nr = tr + 16 * ii;
        bf16x4 o;
#pragma unroll
        for (int j = 0; j < 4; j++) o[j] = f2bf(tile[tc + j][nr]);
        *(bf16x4*)&dst[(n0 + nr) * 512 + a0 + tc] = o;
    }
}

// ---------------------------------------------------------------------------
// 64x64-tile bf16 GEMM core, K=512 (kept for out_gemm where grid is small).
// ---------------------------------------------------------------------------
static __device__ __forceinline__ void gemm_core64(
    const __bf16* __restrict__ A, const __bf16* __restrict__ Bt,
    __bf16* As, __bf16* Bs, int m0, int n0, int t, f32x4 acc[4])
{
    const int w = t >> 6, quad = (t >> 4) & 3, col = t & 15;
    const int sr = t >> 2, sc = (t & 3) * 8;
    for (int kk = 0; kk < 512; kk += 32) {
        __syncthreads();
        async16(&A[(m0 + sr) * 512 + kk + sc], &As[w * 512]);
        async16(&Bt[(n0 + sr) * 512 + kk + sc], &Bs[w * 512]);
        __syncthreads();
        bf16x8 af = *(const bf16x8*)&As[(w * 16 + col) * 32 + quad * 8];
#pragma unroll
        for (int ns = 0; ns < 4; ns++) {
            bf16x8 bfr = *(const bf16x8*)&Bs[(ns * 16 + col) * 32 + quad * 8];
            acc[ns] = __builtin_amdgcn_mfma_f32_16x16x32_bf16(af, bfr, acc[ns], 0, 0, 0);
        }
    }
}

// ---------------------------------------------------------------------------
// 128x128-tile bf16 GEMM core, K=512 (m97 structure).
// ---------------------------------------------------------------------------
static __device__ __forceinline__ void gemm_core128(
    const __bf16* __restrict__ A, const __bf16* __restrict__ Bt,
    __bf16* As, __bf16* Bs, int m0, int n0, int t, f32x4 acc[4][4])
{
    const int w = t >> 6, quad = (t >> 4) & 3, col = t & 15;
    const int wr = (w >> 1) * 64, wc = (w & 1) * 64;
    const int sr = t >> 2, sc = (t & 3) * 8;   // staging: 64 rows x 4 chunks per call
    for (int kk = 0; kk < 512; kk += 32) {
        __syncthreads();
        async16(&A[(m0 + sr) * 512 + kk + sc], &As[w * 512]);
        async16(&A[(m0 + 64 + sr) * 512 + kk + sc], &As[2048 + w * 512]);
        async16(&Bt[(n0 + sr) * 512 + kk + sc], &Bs[w * 512]);
        async16(&Bt[(n0 + 64 + sr) * 512 + kk + sc], &Bs[2048 + w * 512]);
        __syncthreads();
        bf16x8 af[4], bfr[4];
#pragma unroll
        for (int i = 0; i < 4; i++)
            af[i] = *(const bf16x8*)&As[(wr + i * 16 + col) * 32 + quad * 8];
#pragma unroll
        for (int i = 0; i < 4; i++)
            bfr[i] = *(const bf16x8*)&Bs[(wc + i * 16 + col) * 32 + quad * 8];
#pragma unroll
        for (int mi = 0; mi < 4; mi++)
#pragma unroll
            for (int ni = 0; ni < 4; ni++)
                acc[mi][ni] = __builtin_amdgcn_mfma_f32_16x16x32_bf16(
                    af[mi], bfr[ni], acc[mi][ni], 0, 0, 0);
    }
}

// ---------------------------------------------------------------------------
// Merged projection GEMMs (128x128 tiles): z=0 q (b,h,pos,c); z=1 k;
// z=2 v transposed (b,h,c,pos); z=3 gate sigmoid (m,512).
// ---------------------------------------------------------------------------
__global__ __launch_bounds__(256) void proj_gemm(
    const __bf16* __restrict__ qdb, const __bf16* __restrict__ mdb,
    const __bf16* __restrict__ qwt, const __bf16* __restrict__ kwt,
    const __bf16* __restrict__ vwt, const __bf16* __restrict__ gwt,
    __bf16* __restrict__ qbuf, __bf16* __restrict__ kbuf,
    __bf16* __restrict__ vt, __bf16* __restrict__ gate,
    const float* __restrict__ gb)
{
    __shared__ __attribute__((aligned(16))) __bf16 As[4096];
    __shared__ __attribute__((aligned(16))) __bf16 Bs[4096];
    const int z = blockIdx.z;
    const __bf16* A = (z == 0 || z == 3) ? qdb : mdb;
    const __bf16* Bt = (z == 0) ? qwt : (z == 1) ? kwt : (z == 2) ? vwt : gwt;
    const int m0 = blockIdx.x * 128, n0 = blockIdx.y * 128;
    f32x4 acc[4][4];
#pragma unroll
    for (int i = 0; i < 4; i++)
#pragma unroll
        for (int j = 0; j < 4; j++) acc[i][j] = (f32x4){0.f, 0.f, 0.f, 0.f};
    gemm_core128(A, Bt, As, Bs, m0, n0, threadIdx.x, acc);

    const int t = threadIdx.x, w = t >> 6, quad = (t >> 4) & 3, col = t & 15;
    const int wr = (w >> 1) * 64, wc = (w & 1) * 64;
#pragma unroll
    for (int mi = 0; mi < 4; mi++) {
#pragma unroll
        for (int ni = 0; ni < 4; ni++) {
            const int ncol = n0 + wc + ni * 16 + col;
#pragma unroll
            for (int r = 0; r < 4; r++) {
                const int m = m0 + wr + mi * 16 + quad * 4 + r;
                const float v = acc[mi][ni][r];
                if (z <= 1) {
                    int b = m >> 10, pos = m & 1023, hh = ncol >> 6, c = ncol & 63;
                    __bf16* o = z ? kbuf : qbuf;
                    o[(((b * 8 + hh) * 1024 + pos) << 6) + c] = f2bf(v);
                } else if (z == 2) {
                    int b = m >> 10, pos = m & 1023, hh = ncol >> 6, c = ncol & 63;
                    vt[((((b * 8 + hh) << 6) + c) << 10) + pos] = f2bf(v);
                } else {
                    float g = 1.0f / (1.0f + __expf(-(v + gb[ncol])));
                    gate[m * 512 + ncol] = f2bf(g);
                }
            }
        }
    }
}

// ---------------------------------------------------------------------------
// Output GEMM: out[m,n] = wavg @ ow_t + output_b  (f32 out)
// ---------------------------------------------------------------------------
__global__ __launch_bounds__(256) void out_gemm(
    const __bf16* __restrict__ A, const __bf16* __restrict__ Bt,
    float* __restrict__ outp, const float* __restrict__ bvec)
{
    __shared__ __attribute__((aligned(16))) __bf16 As[2048];
    __shared__ __attribute__((aligned(16))) __bf16 Bs[2048];
    const int m0 = blockIdx.x * 64, n0 = blockIdx.y * 64;
    f32x4 acc[4];
#pragma unroll
    for (int i = 0; i < 4; i++) acc[i] = (f32x4){0.f, 0.f, 0.f, 0.f};
    gemm_core64(A, Bt, As, Bs, m0, n0, threadIdx.x, acc);

    const int t = threadIdx.x, w = t >> 6, quad = (t >> 4) & 3, col = t & 15;
    const int mrow0 = m0 + w * 16 + quad * 4;
#pragma unroll
    for (int ns = 0; ns < 4; ns++) {
        const int ncol = n0 + ns * 16 + col;
#pragma unroll
        for (int r = 0; r < 4; r++)
            outp[(mrow0 + r) * 512 + ncol] = acc[ns][r] + bvec[ncol];
    }
}

// ---------------------------------------------------------------------------
// Attention, BARRIER-FREE flash. Evidence R4: attn 82.6us, MfmaUtil 4%,
// VALUBusy 15%, HBM 40% -> 80% waits; TLP didn't help (R3->R4) => the
// per-iteration block-wide barrier/vmcnt lockstep is the stall.
// New structure:
//  - NO LDS K/V staging. MFMA fragments load DIRECTLY from global (L2-hot,
//    64B/row per instruction): K A-frags from k_buf[key][d], V^T B-frags
//    from v_t[d][key], Q B-frags from q_buf. Zero __syncthreads in loop.
//  - Each wave independently owns 16 q-rows x 512 keys (kh half). Swapped
//    QK^T (S^T layout); P redistributed q->A-frag via 1.1KB wave-private
//    LDS scratch (lgkmcnt only, same-wave). One end barrier merges halves.
//  - Register ping-pong double-buffer (named sets, all indices static)
//    prefetches K/V/nb one 32-key tile ahead. bias is L1-hot, loaded inline.
//  - XCD swizzle: each XCD owns 4 bh values -> K/V (1MB) L2-resident.
// ---------------------------------------------------------------------------
__global__ __launch_bounds__(128) void attn_kernel(
    const __bf16* __restrict__ qb, const __bf16* __restrict__ kb,
    const __bf16* __restrict__ vt, const float* __restrict__ bias,
    const float* __restrict__ nb, const __bf16* __restrict__ gate,
    float* __restrict__ logits_out, __bf16* __restrict__ wout)
{
    __shared__ __attribute__((aligned(16))) __bf16 psc[2][576];  // per-wave P scratch, 72B pitch
    __shared__ __attribute__((aligned(16))) float ored[1024];    // wave1 O-partial [16q][64d]
    __shared__ float lred[16];

    // XCD swizzle (2048 blocks, 8 XCDs, 256 each): XCD c gets bh in [c*4,c*4+4)
    const int f = blockIdx.y * 64 + blockIdx.x;
    const int sfl = (f & 7) * 256 + (f >> 3);
    const int qx = sfl & 63, bh = sfl >> 6;
    const int b = bh >> 3, h = bh & 7;
    const int q0 = qx * 16;
    const int t = threadIdx.x, lane = t & 63, w = t >> 6;
    const int quad = lane >> 4, col = lane & 15;
    const int kb0 = w * 512;            // this wave's key half

    const __bf16* kg = kb + bh * 65536;             // [key][d=64]
    const __bf16* vg = vt + bh * 65536;             // [d][key=1024]
    float* lg = logits_out + (size_t)(bh * 1024 + q0) * 1024;
    const float* nbr = nb + (size_t)(h * 1024 + q0 + col) * 1024;
    const float* bg = bias + b * 1024;

    // loop-invariant Q B-frags (B rows = q = col)
    const __bf16* qrow = qb + (size_t)(bh * 1024 + q0 + col) * 64;
    const bf16x8 af0 = *(const bf16x8*)&qrow[quad * 8];
    const bf16x8 af1 = *(const bf16x8*)&qrow[32 + quad * 8];

    f32x4 o_acc[4];
#pragma unroll
    for (int i = 0; i < 4; i++) o_acc[i] = (f32x4){0.f, 0.f, 0.f, 0.f};
    float lsum = 0.f;
    __bf16* pw = psc[w];

    // --- tile load: K A-frags (rows=key), V^T B-frags (rows=d), nb vec ---
    auto LOADT = [&](int kt, bf16x8 kA[2][2], bf16x8 vB[4], f32x4 nbv[2]) {
        const int kr = kb0 + kt * 32;
#pragma unroll
        for (int ns = 0; ns < 2; ns++) {
#pragma unroll
            for (int hf = 0; hf < 2; hf++)
                kA[ns][hf] = *(const bf16x8*)&kg[(kr + ns * 16 + col) * 64 + hf * 32 + quad * 8];
            nbv[ns] = *(const f32x4*)&nbr[kr + ns * 16 + quad * 4];
        }
#pragma unroll
        for (int ns = 0; ns < 4; ns++)
            vB[ns] = *(const bf16x8*)&vg[(ns * 16 + col) * 1024 + kr + quad * 8];
    };

    // --- tile compute: QK^T(swapped) -> logits/exp/P -> PV ---
    auto STEP = [&](int kt, bf16x8 kA[2][2], bf16x8 vB[4], f32x4 nbv[2]) {
        const int kr = kb0 + kt * 32;
        float* lrow = lg + col * 1024 + kr;
        __builtin_amdgcn_s_setprio(1);
        f32x4 s0 = (f32x4){0.f, 0.f, 0.f, 0.f}, s1 = s0;
        s0 = __builtin_amdgcn_mfma_f32_16x16x32_bf16(kA[0][0], af0, s0, 0, 0, 0);
        s0 = __builtin_amdgcn_mfma_f32_16x16x32_bf16(kA[0][1], af1, s0, 0, 0, 0);
        s1 = __builtin_amdgcn_mfma_f32_16x16x32_bf16(kA[1][0], af0, s1, 0, 0, 0);
        s1 = __builtin_amdgcn_mfma_f32_16x16x32_bf16(kA[1][1], af1, s1, 0, 0, 0);
        __builtin_amdgcn_s_setprio(0);
#pragma unroll
        for (int ns = 0; ns < 2; ns++) {
            f32x4 raw = ns ? s1 : s0;
            __builtin_nontemporal_store(raw, (f32x4*)&lrow[ns * 16 + quad * 4]);
            f32x4 bv = *(const f32x4*)&bg[kr + ns * 16 + quad * 4];   // L1-hot
            bf16x4 pk;
#pragma unroll
            for (int r = 0; r < 4; r++) {
                float p = __expf(raw[r] + bv[r] + nbv[ns][r]);
                lsum += p;
                pk[r] = f2bf(p);
            }
            *(bf16x4*)&pw[col * 36 + ns * 16 + quad * 4] = pk;   // P[q=col][key]
        }
        bf16x8 pf = *(const bf16x8*)&pw[col * 36 + quad * 8];    // A-frag: q=col, keys quad*8..
        __builtin_amdgcn_s_setprio(1);
#pragma unroll
        for (int ns = 0; ns < 4; ns++)
            o_acc[ns] = __builtin_amdgcn_mfma_f32_16x16x32_bf16(pf, vB[ns], o_acc[ns], 0, 0, 0);
        __builtin_amdgcn_s_setprio(0);
    };

    bf16x8 kAa[2][2], vBa[4], kAb[2][2], vBb[4];
    f32x4 nba[2], nbb2[2];
    LOADT(0, kAa, vBa, nba);
#pragma unroll
    for (int kt = 0; kt < 16; kt += 2) {
        LOADT(kt + 1, kAb, vBb, nbb2);
        STEP(kt, kAa, vBa, nba);
        if (kt + 2 < 16) LOADT(kt + 2, kAa, vBa, nba);
        STEP(kt + 1, kAb, vBb, nbb2);
    }

    // per-wave l-sum for q=col (sum over this wave's 512 keys)
    lsum += __shfl_xor(lsum, 16, 64);
    lsum += __shfl_xor(lsum, 32, 64);

    if (w == 1) {
#pragma unroll
        for (int ns = 0; ns < 4; ns++)
#pragma unroll
            for (int r = 0; r < 4; r++)
                ored[(quad * 4 + r) * 64 + ns * 16 + col] = o_acc[ns][r];
        if (quad == 0) lred[col] = lsum;
    }
    __syncthreads();
    if (w == 0) {
        const float inv = 1.0f / (lsum + lred[col]);   // valid for q = col
        float invr[4];
#pragma unroll
        for (int r = 0; r < 4; r++) invr[r] = __shfl(inv, quad * 4 + r, 64);
#pragma unroll
        for (int ns = 0; ns < 4; ns++) {
            const int c = ns * 16 + col;
#pragma unroll
            for (int r = 0; r < 4; r++) {
                const int pos = q0 + quad * 4 + r;
                float ov = (o_acc[ns][r] + ored[(quad * 4 + r) * 64 + c]) * invr[r];
                float gv = (float)gate[(b * 1024 + pos) * 512 + h * 64 + c];
                wout[(b * 1024 + pos) * 512 + h * 64 + c] = f2bf(ov * gv);
            }
        }
    }
}

// ---------------------------------------------------------------------------
extern "C" void kernel_launch(void* const* d_in, const int* in_sizes, int n_in,
                              void* d_out, int out_size, void* d_ws, size_t ws_size,
                              hipStream_t stream) {
    (void)in_sizes; (void)n_in; (void)out_size; (void)ws_size;
    const float* q_data   = (const float*)d_in[0];
    const float* m_data   = (const float*)d_in[1];
    const float* bias     = (const float*)d_in[2];
    const float* nbb      = (const float*)d_in[3];
    const float* query_w  = (const float*)d_in[4];
    const float* key_w    = (const float*)d_in[5];
    const float* value_w  = (const float*)d_in[6];
    const float* gating_w = (const float*)d_in[7];
    const float* gating_b = (const float*)d_in[8];
    const float* output_w = (const float*)d_in[9];
    const float* output_b = (const float*)d_in[10];

    char* ws = (char*)d_ws;
    __bf16* qd_b  = (__bf16*)(ws + 0);         // 4 MiB (reused as wavg later)
    __bf16* md_b  = (__bf16*)(ws + 4194304);   // 4 MiB
    __bf16* qw_t  = (__bf16*)(ws + 8388608);   // 512 KiB each
    __bf16* kw_t  = (__bf16*)(ws + 8912896);
    __bf16* vw_t  = (__bf16*)(ws + 9437184);
    __bf16* gw_t  = (__bf16*)(ws + 9961472);
    __bf16* ow_t  = (__bf16*)(ws + 10485760);
    __bf16* q_buf = (__bf16*)(ws + 11010048);  // 4 MiB (b,h,pos,c)
    __bf16* k_buf = (__bf16*)(ws + 15204352);  // 4 MiB (b,h,pos,c)
    __bf16* v_t   = (__bf16*)(ws + 19398656);  // 4 MiB (b,h,c,pos)
    __bf16* gate  = (__bf16*)(ws + 23592960);  // 4 MiB (m,512)
    __bf16* wavg  = (__bf16*)(ws + 0);         // overlays qd_b (dead by then)

    float* outp = (float*)d_out;
    float* logits = outp + (4 * 1024 * 512);

    cast_data<<<dim3(1024), dim3(256), 0, stream>>>(q_data, m_data, qd_b, md_b);
    transpose_cast<<<dim3(8, 8, 5), dim3(256), 0, stream>>>(
        query_w, key_w, value_w, gating_w, output_w, qw_t, kw_t, vw_t, gw_t, ow_t);
    proj_gemm<<<dim3(32, 4, 4), dim3(256), 0, stream>>>(
        qd_b, md_b, qw_t, kw_t, vw_t, gw_t, q_buf, k_buf, v_t, gate, gating_b);
    attn_kernel<<<dim3(64, 32), dim3(128), 0, stream>>>(
        q_buf, k_buf, v_t, bias, nbb, gate, logits, wavg);
    out_gemm<<<dim3(64, 8), dim3(256), 0, stream>>>(wavg, ow_t, outp, output_b);
}